// Round 4
// baseline (477.171 us; speedup 1.0000x reference)
//
#include <hip/hip_runtime.h>
#include <cstdint>
#include <cstddef>

// GAT layer, N=8192, F=128.  Round 4: 16-row waves + deep adj prefetch.
// k1  : Wh = h@W -> WhT fp16 [f][row] (for k1b) + Bp (16x16x32 B-frag order, for k2)
// k1b : s1,s2 per row; global max(s2) via encoded atomicMax
// k1c : row factors K12=(exp(s1-c), exp(.2 s1-c)); col factors EF=(exp(s2), exp(.2 s2))
// k2  : mfma_f32_16x16x32_f16; 1 wave = 16 rows x 128 f, j chunked (S=8);
//       NO LDS/barriers; adj 4-iter register-ring prefetch (512 B/row in flight);
//       score p = max(E*k1, F*k2) (leaky=max(t,.2t), exp monotone) -> branch-free.
// k3  : combine S partials, ELU, store.
// R3 post-mortem: k2 ~150us, adj at ~28% BW eff (thin 128 B/row granules, occ 2/SIMD).

#define NROW 8192
#define FDIM 128

typedef _Float16 f16;
typedef f16 f16x8 __attribute__((ext_vector_type(8)));
typedef float f32x4 __attribute__((ext_vector_type(4)));

// workspace byte offsets
#define WS_WHT 0u                            // f16 WhT[128][8192]        : 2 MiB
#define WS_BP  (2u*1024u*1024u)              // f16 Bp[256][8][64][8]     : 2 MiB
#define WS_S12 (4u*1024u*1024u)              // float2 s12[8192]          : 64 KiB
#define WS_K12 (WS_S12 + 64u*1024u)          // float2 K12[8192]          : 64 KiB
#define WS_EF  (WS_K12 + 64u*1024u)          // float2 EF[8192]           : 64 KiB
#define WS_M2  (WS_EF + 64u*1024u)           // unsigned M2 key (pad 4K)
#define WS_PWS (WS_M2 + 4u*1024u)            // float Pws[S][8192][128]   : S*4 MiB

// ---------------- k1: Wh = h @ W; write WhT fp16 and Bp ----------------
__global__ __launch_bounds__(256) void k1_wh(const float* __restrict__ h,
                                             const float* __restrict__ W,
                                             f16* __restrict__ WhT,
                                             f16* __restrict__ Bp,
                                             unsigned* __restrict__ M2key) {
  __shared__ float hT[128 * 36];  // hT[k][r], stride 36
  const int t = (int)threadIdx.x;
  const int rb = (int)blockIdx.x * 32;
  if (blockIdx.x == 0 && t == 0) *M2key = 0u;
  const f32x4* hv = (const f32x4*)(h + (size_t)rb * FDIM);
#pragma unroll
  for (int i = 0; i < 4; ++i) {
    int fidx = t + i * 256;
    f32x4 v = hv[fidx];
    int e0 = fidx * 4;
    int r = e0 >> 7, k = e0 & 127;
    hT[(k + 0) * 36 + r] = v[0];
    hT[(k + 1) * 36 + r] = v[1];
    hT[(k + 2) * 36 + r] = v[2];
    hT[(k + 3) * 36 + r] = v[3];
  }
  __syncthreads();
  const int f = t & 127, rh = t >> 7;
  f32x4 z = {0.f, 0.f, 0.f, 0.f};
  f32x4 acc0 = z, acc1 = z, acc2 = z, acc3 = z;
  for (int k = 0; k < 128; ++k) {
    float w = W[k * FDIM + f];
    const f32x4* hp = (const f32x4*)(hT + k * 36 + rh * 16);
    acc0 += hp[0] * w;
    acc1 += hp[1] * w;
    acc2 += hp[2] * w;
    acc3 += hp[3] * w;
  }
  union { f16 hx[16]; uint4 u[2]; } pk;
#pragma unroll
  for (int q = 0; q < 4; ++q) {
    pk.hx[0 + q]  = (f16)acc0[q];   // hx[i] = Wh[rb + rh*16 + i][f]
    pk.hx[4 + q]  = (f16)acc1[q];
    pk.hx[8 + q]  = (f16)acc2[q];
    pk.hx[12 + q] = (f16)acc3[q];
  }
  // WhT [f][row]
  uint4* dst = (uint4*)(WhT + (size_t)f * NROW + rb + rh * 16);
  dst[0] = pk.u[0];
  dst[1] = pk.u[1];
  // Bp[jt=row/32][nt=f/16][lane=q*16+(f&15)][e] = Wh[jt*32 + q*8 + e][f]
  // this thread: jt = blockIdx.x, rows rh*16+i -> q = 2*rh + (i>>3), e = i&7
  f16* bdst = Bp + (size_t)blockIdx.x * 4096 + (size_t)(f >> 4) * 512
                 + (size_t)(2 * rh) * 128 + (size_t)(f & 15) * 8;
  *(uint4*)bdst = pk.u[0];          // q = 2*rh
  *(uint4*)(bdst + 128) = pk.u[1];  // q = 2*rh + 1 (+16 lanes * 8)
}

// ---------------- k1b: s1,s2 per row (f-split x4); encoded atomicMax M2 ----------------
__global__ __launch_bounds__(256) void k1b_s(const f16* __restrict__ WhT,
                                             const float* __restrict__ a,
                                             float2* __restrict__ s12,
                                             unsigned* __restrict__ M2key) {
  __shared__ float part[2][4][64];
  const int l = (int)threadIdx.x & 63;
  const int fc = (int)threadIdx.x >> 6;
  const int r = (int)blockIdx.x * 64 + l;
  float s1 = 0.f, s2 = 0.f;
  for (int f = fc * 32; f < fc * 32 + 32; ++f) {
    float w = (float)WhT[(size_t)f * NROW + r];
    s1 = fmaf(w, a[f], s1);
    s2 = fmaf(w, a[128 + f], s2);
  }
  part[0][fc][l] = s1;
  part[1][fc][l] = s2;
  __syncthreads();
  if (fc == 0) {
    s1 = part[0][0][l] + part[0][1][l] + part[0][2][l] + part[0][3][l];
    s2 = part[1][0][l] + part[1][1][l] + part[1][2][l] + part[1][3][l];
    s12[r] = make_float2(s1, s2);
    float mx = s2;
#pragma unroll
    for (int off = 32; off; off >>= 1) mx = fmaxf(mx, __shfl_xor(mx, off, 64));
    if (l == 0) {
      unsigned key = __float_as_uint(mx);
      key = (key & 0x80000000u) ? ~key : (key | 0x80000000u);
      atomicMax(M2key, key);
    }
  }
}

// ---------------- k1c: per-index exp factors ----------------
__global__ __launch_bounds__(256) void k1c_prep(const float2* __restrict__ s12,
                                                const unsigned* __restrict__ M2key,
                                                float2* __restrict__ K12,
                                                float2* __restrict__ EF) {
  int j = (int)blockIdx.x * 256 + (int)threadIdx.x;
  unsigned key = *M2key;
  float M2 = (key & 0x80000000u) ? __uint_as_float(key ^ 0x80000000u)
                                 : __uint_as_float(~key);
  float2 s = s12[j];
  float c = s.x + M2;
  c = fmaxf(c, 0.2f * c);  // c >= leaky(s1 + s2_j) for all j  =>  p <= 1
  K12[j] = make_float2(__expf(s.x - c), __expf(0.2f * s.x - c));
  EF[j] = make_float2(__expf(s.y), __expf(0.2f * s.y));
}

// ---------------- k2: barrier-free fused masked-softmax @ Wh (16-row waves) ----------------
// wave wid: rg = wid&511 (16-row group), c = wid>>9 (j chunk). lane: m=L&15 (row), kq=L>>4.
// per 32-j iter: lane's 8 j's contiguous (j0 + kq*8 + it*32 + 0..7); adj 4-deep ring.
__global__ __launch_bounds__(256) void k2_main(const int* __restrict__ adj,
                                               const f16* __restrict__ Bp,
                                               const float2* __restrict__ K12,
                                               const float* __restrict__ EF,
                                               float* __restrict__ Pws,
                                               float* __restrict__ Dws,
                                               int jspan) {
  const int tid = (int)threadIdx.x;
  const int L = tid & 63, w = tid >> 6;
  const int wid = (int)blockIdx.x * 4 + w;
  const int rg = wid & 511;
  const int c = wid >> 9;
  const int rb = rg * 16;
  const int m = L & 15, kq = L >> 4;   // kq in 0..3
  const int row = rb + m;
  const int j0 = c * jspan;
  const int niter = jspan >> 5;

  const float2 kk = K12[row];
  const float kap1 = kk.x, kap2 = kk.y;

  const int* ap = adj + (size_t)row * NROW + j0 + kq * 8;
  const float* ep = EF ? (EF + 2 * (size_t)(j0 + kq * 8)) : EF;  // float2 flattened
  const f16* bp = Bp + (size_t)(j0 >> 5) * 4096 + (size_t)L * 8;

  // adj ring: slot s holds iters it ≡ s (mod 4); 4-iter (≈1400 cyc) latency budget
  int4 A[4][2];
#pragma unroll
  for (int s = 0; s < 4; ++s) {
    A[s][0] = *(const int4*)(ap + s * 32);
    A[s][1] = *(const int4*)(ap + s * 32 + 4);
  }
  // EF: 1 iter ahead (L2-resident)
  f32x4 E[4];
#pragma unroll
  for (int q = 0; q < 4; ++q) E[q] = *(const f32x4*)(ep + q * 4);

  f32x4 z = {0.f, 0.f, 0.f, 0.f};
  f32x4 acc[8] = {z, z, z, z, z, z, z, z};
  float dloc = 0.f;

  for (int ii = 0; ii < niter; ii += 4) {
#pragma unroll
    for (int s = 0; s < 4; ++s) {
      const int it = ii + s;
      const f16* bt = bp + (size_t)it * 4096;
      f16x8 B0 = *(const f16x8*)(bt);
      f16x8 B1 = *(const f16x8*)(bt + 512);
      f16x8 B2 = *(const f16x8*)(bt + 1024);
      f16x8 B3 = *(const f16x8*)(bt + 1536);
      f16x8 B4 = *(const f16x8*)(bt + 2048);
      f16x8 B5 = *(const f16x8*)(bt + 2560);
      f16x8 B6 = *(const f16x8*)(bt + 3072);
      f16x8 B7 = *(const f16x8*)(bt + 3584);

      // branch-free score: p = max(E*kap1, F*kap2) = exp(leaky(s1+s2)-c), then mask
      f16x8 af;
      {
        const int4 a0 = A[s][0], a1 = A[s][1];
        float p;
        p = fmaxf(E[0][0] * kap1, E[0][1] * kap2); p = (a0.x > 0) ? p : 0.f; dloc += p; af[0] = (f16)p;
        p = fmaxf(E[0][2] * kap1, E[0][3] * kap2); p = (a0.y > 0) ? p : 0.f; dloc += p; af[1] = (f16)p;
        p = fmaxf(E[1][0] * kap1, E[1][1] * kap2); p = (a0.z > 0) ? p : 0.f; dloc += p; af[2] = (f16)p;
        p = fmaxf(E[1][2] * kap1, E[1][3] * kap2); p = (a0.w > 0) ? p : 0.f; dloc += p; af[3] = (f16)p;
        p = fmaxf(E[2][0] * kap1, E[2][1] * kap2); p = (a1.x > 0) ? p : 0.f; dloc += p; af[4] = (f16)p;
        p = fmaxf(E[2][2] * kap1, E[2][3] * kap2); p = (a1.y > 0) ? p : 0.f; dloc += p; af[5] = (f16)p;
        p = fmaxf(E[3][0] * kap1, E[3][1] * kap2); p = (a1.z > 0) ? p : 0.f; dloc += p; af[6] = (f16)p;
        p = fmaxf(E[3][2] * kap1, E[3][3] * kap2); p = (a1.w > 0) ? p : 0.f; dloc += p; af[7] = (f16)p;
      }

      // refill adj slot s for iter it+4 (dead reload on tail)
      {
        const int itn = (it + 4 < niter) ? it + 4 : it;
        A[s][0] = *(const int4*)(ap + itn * 32);
        A[s][1] = *(const int4*)(ap + itn * 32 + 4);
      }
      // refill E for iter it+1
      {
        const int itn = (it + 1 < niter) ? it + 1 : it;
#pragma unroll
        for (int q = 0; q < 4; ++q) E[q] = *(const f32x4*)(ep + itn * 64 + q * 4);
      }

      acc[0] = __builtin_amdgcn_mfma_f32_16x16x32_f16(af, B0, acc[0], 0, 0, 0);
      acc[1] = __builtin_amdgcn_mfma_f32_16x16x32_f16(af, B1, acc[1], 0, 0, 0);
      acc[2] = __builtin_amdgcn_mfma_f32_16x16x32_f16(af, B2, acc[2], 0, 0, 0);
      acc[3] = __builtin_amdgcn_mfma_f32_16x16x32_f16(af, B3, acc[3], 0, 0, 0);
      acc[4] = __builtin_amdgcn_mfma_f32_16x16x32_f16(af, B4, acc[4], 0, 0, 0);
      acc[5] = __builtin_amdgcn_mfma_f32_16x16x32_f16(af, B5, acc[5], 0, 0, 0);
      acc[6] = __builtin_amdgcn_mfma_f32_16x16x32_f16(af, B6, acc[6], 0, 0, 0);
      acc[7] = __builtin_amdgcn_mfma_f32_16x16x32_f16(af, B7, acc[7], 0, 0, 0);
    }
  }

  // denominator: sum quads (lanes m, m+16, m+32, m+48)
  dloc += __shfl_xor(dloc, 16, 64);
  dloc += __shfl_xor(dloc, 32, 64);
  if (L < 16) Dws[(size_t)c * NROW + rb + L] = dloc;

  // numerator partials: C/D layout col=L&15, row=(L>>4)*4+reg
  float* P = Pws + ((size_t)c * NROW + rb) * FDIM + (L & 15);
#pragma unroll
  for (int nt = 0; nt < 8; ++nt) {
#pragma unroll
    for (int reg = 0; reg < 4; ++reg) {
      int rr = kq * 4 + reg;
      P[(size_t)rr * FDIM + nt * 16] = acc[nt][reg];
    }
  }
}

// ---------------- k3: combine S partials, ELU ----------------
__global__ __launch_bounds__(256) void k3_comb(const float* __restrict__ Pws,
                                               const float* __restrict__ Dws,
                                               float* __restrict__ out, int S) {
  int g = (int)blockIdx.x * 256 + (int)threadIdx.x;  // 0..262143
  int r = g >> 5, f4 = g & 31;
  f32x4 s = {0.f, 0.f, 0.f, 0.f};
  float den = 0.f;
  for (int c2 = 0; c2 < S; ++c2) {
    s += *(const f32x4*)(Pws + ((size_t)c2 * NROW + r) * FDIM + f4 * 4);
    den += Dws[(size_t)c2 * NROW + r];
  }
  float inv = 1.0f / den;
  f32x4 o;
#pragma unroll
  for (int e = 0; e < 4; ++e) {
    float x = s[e] * inv;
    o[e] = x > 0.f ? x : expm1f(x);
  }
  *(f32x4*)(out + (size_t)r * FDIM + f4 * 4) = o;
}

extern "C" void kernel_launch(void* const* d_in, const int* in_sizes, int n_in,
                              void* d_out, int out_size, void* d_ws, size_t ws_size,
                              hipStream_t stream) {
  const float* h = (const float*)d_in[0];
  const int* adj = (const int*)d_in[1];
  const float* W = (const float*)d_in[2];
  const float* a = (const float*)d_in[3];
  float* out = (float*)d_out;
  char* ws = (char*)d_ws;
  f16* WhT = (f16*)(ws + WS_WHT);
  f16* Bp = (f16*)(ws + WS_BP);
  float2* s12 = (float2*)(ws + WS_S12);
  float2* K12 = (float2*)(ws + WS_K12);
  float2* EF = (float2*)(ws + WS_EF);
  unsigned* M2 = (unsigned*)(ws + WS_M2);

  const size_t partial_bytes = (size_t)NROW * FDIM * 4;  // 4 MiB per chunk
  int S = (ws_size >= WS_PWS + 8 * partial_bytes + 8 * NROW * 4) ? 8 : 2;
  float* Pws = (float*)(ws + WS_PWS);
  float* Dws = (float*)(ws + WS_PWS + (size_t)S * partial_bytes);
  int jspan = NROW / S;

  k1_wh<<<dim3(256), dim3(256), 0, stream>>>(h, W, WhT, Bp, M2);
  k1b_s<<<dim3(128), dim3(256), 0, stream>>>(WhT, a, s12, M2);
  k1c_prep<<<dim3(32), dim3(256), 0, stream>>>(s12, M2, K12, EF);
  k2_main<<<dim3(128 * S), dim3(256), 0, stream>>>(adj, Bp, K12, (const float*)EF, Pws, Dws, jspan);
  k3_comb<<<dim3(1024), dim3(256), 0, stream>>>(Pws, Dws, out, S);
}

// Round 5
// 470.328 us; speedup vs baseline: 1.0145x; 1.0145x over previous
//
#include <hip/hip_runtime.h>
#include <cstdint>
#include <cstddef>

// GAT layer, N=8192, F=128.  Round 5: vmcnt-ordering fix (fast EF refill BEFORE slow
// adj refill so the per-iter waitcnt never chains behind the HBM stream), f16 EF with
// rescaled factors (all in (0,1], no overflow), denominator via ones-MFMA.
// R4 post-mortem: ~850 cyc/wave-iter = one exposed HBM latency per iter, because EF
// (L2-fast, needed next iter) was queued after adj (HBM-slow) -> vmcnt chained them.

#define NROW 8192
#define FDIM 128

typedef _Float16 f16;
typedef f16 f16x8 __attribute__((ext_vector_type(8)));
typedef float f32x4 __attribute__((ext_vector_type(4)));

// workspace byte offsets
#define WS_WHT 0u                            // f16 WhT[128][8192]        : 2 MiB
#define WS_BP  (2u*1024u*1024u)              // f16 Bp[256][8][64][8]     : 2 MiB
#define WS_S12 (4u*1024u*1024u)              // float2 s12[8192]          : 64 KiB
#define WS_K12 (WS_S12 + 64u*1024u)          // float2 K12[8192]          : 64 KiB
#define WS_EF  (WS_K12 + 64u*1024u)          // f16 Eh[8192]; f16 Fh[8192]: 32 KiB
#define WS_M2  (WS_EF + 64u*1024u)           // unsigned M2 key (pad 4K)
#define WS_PWS (WS_M2 + 4u*1024u)            // float Pws[S][8192][128]   : S*4 MiB

// ---------------- k1: Wh = h @ W; write WhT fp16 and Bp ----------------
__global__ __launch_bounds__(256) void k1_wh(const float* __restrict__ h,
                                             const float* __restrict__ W,
                                             f16* __restrict__ WhT,
                                             f16* __restrict__ Bp,
                                             unsigned* __restrict__ M2key) {
  __shared__ float hT[128 * 36];  // hT[k][r], stride 36
  const int t = (int)threadIdx.x;
  const int rb = (int)blockIdx.x * 32;
  if (blockIdx.x == 0 && t == 0) *M2key = 0u;
  const f32x4* hv = (const f32x4*)(h + (size_t)rb * FDIM);
#pragma unroll
  for (int i = 0; i < 4; ++i) {
    int fidx = t + i * 256;
    f32x4 v = hv[fidx];
    int e0 = fidx * 4;
    int r = e0 >> 7, k = e0 & 127;
    hT[(k + 0) * 36 + r] = v[0];
    hT[(k + 1) * 36 + r] = v[1];
    hT[(k + 2) * 36 + r] = v[2];
    hT[(k + 3) * 36 + r] = v[3];
  }
  __syncthreads();
  const int f = t & 127, rh = t >> 7;
  f32x4 z = {0.f, 0.f, 0.f, 0.f};
  f32x4 acc0 = z, acc1 = z, acc2 = z, acc3 = z;
  for (int k = 0; k < 128; ++k) {
    float w = W[k * FDIM + f];
    const f32x4* hp = (const f32x4*)(hT + k * 36 + rh * 16);
    acc0 += hp[0] * w;
    acc1 += hp[1] * w;
    acc2 += hp[2] * w;
    acc3 += hp[3] * w;
  }
  union { f16 hx[16]; uint4 u[2]; } pk;
#pragma unroll
  for (int q = 0; q < 4; ++q) {
    pk.hx[0 + q]  = (f16)acc0[q];   // hx[i] = Wh[rb + rh*16 + i][f]
    pk.hx[4 + q]  = (f16)acc1[q];
    pk.hx[8 + q]  = (f16)acc2[q];
    pk.hx[12 + q] = (f16)acc3[q];
  }
  // WhT [f][row]
  uint4* dst = (uint4*)(WhT + (size_t)f * NROW + rb + rh * 16);
  dst[0] = pk.u[0];
  dst[1] = pk.u[1];
  // Bp[jt=row/32][nt=f/16][lane=q*16+(f&15)][e] = Wh[jt*32 + q*8 + e][f]
  f16* bdst = Bp + (size_t)blockIdx.x * 4096 + (size_t)(f >> 4) * 512
                 + (size_t)(2 * rh) * 128 + (size_t)(f & 15) * 8;
  *(uint4*)bdst = pk.u[0];          // q = 2*rh
  *(uint4*)(bdst + 128) = pk.u[1];  // q = 2*rh + 1
}

// ---------------- k1b: s1,s2 per row (f-split x4); encoded atomicMax M2 ----------------
__global__ __launch_bounds__(256) void k1b_s(const f16* __restrict__ WhT,
                                             const float* __restrict__ a,
                                             float2* __restrict__ s12,
                                             unsigned* __restrict__ M2key) {
  __shared__ float part[2][4][64];
  const int l = (int)threadIdx.x & 63;
  const int fc = (int)threadIdx.x >> 6;
  const int r = (int)blockIdx.x * 64 + l;
  float s1 = 0.f, s2 = 0.f;
  for (int f = fc * 32; f < fc * 32 + 32; ++f) {
    float w = (float)WhT[(size_t)f * NROW + r];
    s1 = fmaf(w, a[f], s1);
    s2 = fmaf(w, a[128 + f], s2);
  }
  part[0][fc][l] = s1;
  part[1][fc][l] = s2;
  __syncthreads();
  if (fc == 0) {
    s1 = part[0][0][l] + part[0][1][l] + part[0][2][l] + part[0][3][l];
    s2 = part[1][0][l] + part[1][1][l] + part[1][2][l] + part[1][3][l];
    s12[r] = make_float2(s1, s2);
    float mx = s2;
#pragma unroll
    for (int off = 32; off; off >>= 1) mx = fmaxf(mx, __shfl_xor(mx, off, 64));
    if (l == 0) {
      unsigned key = __float_as_uint(mx);
      key = (key & 0x80000000u) ? ~key : (key | 0x80000000u);
      atomicMax(M2key, key);
    }
  }
}

// ---------------- k1c: rescaled per-index exp factors (all in (0,1], f16-safe) ----------
// p_ij = max(E'_j*kap1_i, F'_j*kap2_i) with E'=exp(s2-M2), F'=exp(.2(s2-M2)),
// kap1 = exp(min(0,.8u)), kap2 = exp(-.8*max(u,0)), u = s1+M2.  (== exp(leaky-c), exact.)
__global__ __launch_bounds__(256) void k1c_prep(const float2* __restrict__ s12,
                                                const unsigned* __restrict__ M2key,
                                                float2* __restrict__ K12,
                                                f16* __restrict__ Eh,
                                                f16* __restrict__ Fh) {
  int j = (int)blockIdx.x * 256 + (int)threadIdx.x;
  unsigned key = *M2key;
  float M2 = (key & 0x80000000u) ? __uint_as_float(key ^ 0x80000000u)
                                 : __uint_as_float(~key);
  float2 s = s12[j];
  float u = s.x + M2;
  K12[j] = make_float2(__expf(fminf(0.f, 0.8f * u)), __expf(-0.8f * fmaxf(u, 0.f)));
  Eh[j] = (f16)__expf(s.y - M2);
  Fh[j] = (f16)__expf(0.2f * (s.y - M2));
}

// ---------------- k2: barrier-free fused masked-softmax @ Wh ----------------
// wave wid: rg = wid&511 (16 rows), c = wid>>9 (j chunk). lane: m=L&15 (row), kq=L>>4.
// Per-iter VMEM order (critical): B(L2) -> [af build] -> EF refill(L2) -> adj refill(HBM)
// so no consumer's waitcnt chains behind the slow adj stream. 2-deep rings, unroll x2.
__global__ __launch_bounds__(256) void k2_main(const int* __restrict__ adj,
                                               const f16* __restrict__ Bp,
                                               const float2* __restrict__ K12,
                                               const f16* __restrict__ Eh,
                                               const f16* __restrict__ Fh,
                                               float* __restrict__ Pws,
                                               float* __restrict__ Dws,
                                               int jspan) {
  const int tid = (int)threadIdx.x;
  const int L = tid & 63, w = tid >> 6;
  const int wid = (int)blockIdx.x * 4 + w;
  const int rg = wid & 511;
  const int c = wid >> 9;
  const int rb = rg * 16;
  const int m = L & 15, kq = L >> 4;
  const int row = rb + m;
  const int j0 = c * jspan;
  const int niter = jspan >> 5;

  const float2 kk = K12[row];
  f16x8 kap1v, kap2v, bones;
#pragma unroll
  for (int i = 0; i < 8; ++i) {
    kap1v[i] = (f16)kk.x;
    kap2v[i] = (f16)kk.y;
    bones[i] = (f16)1.0f;
  }

  const int* ap = adj + (size_t)row * NROW + j0 + kq * 8;
  const f16* ehp = Eh + j0 + kq * 8;
  const f16* fhp = Fh + j0 + kq * 8;
  const f16* bp = Bp + (size_t)(j0 >> 5) * 4096 + (size_t)L * 8;

  // 2-deep rings: slot s holds iter (it: it&1==s)
  int4 A0s[2], A1s[2];
  f16x8 Er[2], Fr[2];
#pragma unroll
  for (int s = 0; s < 2; ++s) {
    A0s[s] = *(const int4*)(ap + s * 32);
    A1s[s] = *(const int4*)(ap + s * 32 + 4);
    Er[s] = *(const f16x8*)(ehp + s * 32);
    Fr[s] = *(const f16x8*)(fhp + s * 32);
  }

  f32x4 z = {0.f, 0.f, 0.f, 0.f};
  f32x4 acc[8] = {z, z, z, z, z, z, z, z};
  f32x4 accd = z;

  for (int ii = 0; ii < niter; ii += 2) {
#pragma unroll
    for (int s = 0; s < 2; ++s) {
      const int it = ii + s;
      // (1) B loads — L2-hot, consumed by MFMAs below
      const f16* bt = bp + (size_t)it * 4096;
      f16x8 B0 = *(const f16x8*)(bt);
      f16x8 B1 = *(const f16x8*)(bt + 512);
      f16x8 B2 = *(const f16x8*)(bt + 1024);
      f16x8 B3 = *(const f16x8*)(bt + 1536);
      f16x8 B4 = *(const f16x8*)(bt + 2048);
      f16x8 B5 = *(const f16x8*)(bt + 2560);
      f16x8 B6 = *(const f16x8*)(bt + 3072);
      f16x8 B7 = *(const f16x8*)(bt + 3584);

      // (2) score build from ring slot s (issued 2 iters ago)
      f16x8 t = __builtin_elementwise_max(Er[s] * kap1v, Fr[s] * kap2v);
      f16x8 af;
      {
        const int4 a0 = A0s[s], a1 = A1s[s];
        af[0] = (a0.x > 0) ? t[0] : (f16)0.f;
        af[1] = (a0.y > 0) ? t[1] : (f16)0.f;
        af[2] = (a0.z > 0) ? t[2] : (f16)0.f;
        af[3] = (a0.w > 0) ? t[3] : (f16)0.f;
        af[4] = (a1.x > 0) ? t[4] : (f16)0.f;
        af[5] = (a1.y > 0) ? t[5] : (f16)0.f;
        af[6] = (a1.z > 0) ? t[6] : (f16)0.f;
        af[7] = (a1.w > 0) ? t[7] : (f16)0.f;
      }

      // (3) FAST refills first: EF for it+2 (L2) — must precede adj in issue order
      const int itn = (it + 2 < niter) ? it + 2 : it;
      Er[s] = *(const f16x8*)(ehp + itn * 32);
      Fr[s] = *(const f16x8*)(fhp + itn * 32);
      // (4) SLOW refill last: adj for it+2 (HBM/L3) — newest in queue
      A0s[s] = *(const int4*)(ap + itn * 32);
      A1s[s] = *(const int4*)(ap + itn * 32 + 4);

      // (5) MFMAs (wait only on B: vmcnt leaves EF+adj outstanding)
      acc[0] = __builtin_amdgcn_mfma_f32_16x16x32_f16(af, B0, acc[0], 0, 0, 0);
      acc[1] = __builtin_amdgcn_mfma_f32_16x16x32_f16(af, B1, acc[1], 0, 0, 0);
      acc[2] = __builtin_amdgcn_mfma_f32_16x16x32_f16(af, B2, acc[2], 0, 0, 0);
      acc[3] = __builtin_amdgcn_mfma_f32_16x16x32_f16(af, B3, acc[3], 0, 0, 0);
      acc[4] = __builtin_amdgcn_mfma_f32_16x16x32_f16(af, B4, acc[4], 0, 0, 0);
      acc[5] = __builtin_amdgcn_mfma_f32_16x16x32_f16(af, B5, acc[5], 0, 0, 0);
      acc[6] = __builtin_amdgcn_mfma_f32_16x16x32_f16(af, B6, acc[6], 0, 0, 0);
      acc[7] = __builtin_amdgcn_mfma_f32_16x16x32_f16(af, B7, acc[7], 0, 0, 0);
      // denominator: row-sums of P via ones-B (same quantized p as numerator)
      accd = __builtin_amdgcn_mfma_f32_16x16x32_f16(af, bones, accd, 0, 0, 0);
    }
  }

  // denominator: accd[reg] = D[row kq*4+reg][col m] — all cols equal; take m==0 lanes
  if (m == 0) {
#pragma unroll
    for (int reg = 0; reg < 4; ++reg)
      Dws[(size_t)c * NROW + rb + kq * 4 + reg] = accd[reg];
  }

  // numerator partials: C/D layout col=L&15, row=kq*4+reg
  float* P = Pws + ((size_t)c * NROW + rb) * FDIM + m;
#pragma unroll
  for (int nt = 0; nt < 8; ++nt) {
#pragma unroll
    for (int reg = 0; reg < 4; ++reg) {
      int rr = kq * 4 + reg;
      P[(size_t)rr * FDIM + nt * 16] = acc[nt][reg];
    }
  }
}

// ---------------- k3: combine S partials, ELU ----------------
__global__ __launch_bounds__(256) void k3_comb(const float* __restrict__ Pws,
                                               const float* __restrict__ Dws,
                                               float* __restrict__ out, int S) {
  int g = (int)blockIdx.x * 256 + (int)threadIdx.x;  // 0..262143
  int r = g >> 5, f4 = g & 31;
  f32x4 s = {0.f, 0.f, 0.f, 0.f};
  float den = 0.f;
  for (int c2 = 0; c2 < S; ++c2) {
    s += *(const f32x4*)(Pws + ((size_t)c2 * NROW + r) * FDIM + f4 * 4);
    den += Dws[(size_t)c2 * NROW + r];
  }
  float inv = 1.0f / den;
  f32x4 o;
#pragma unroll
  for (int e = 0; e < 4; ++e) {
    float x = s[e] * inv;
    o[e] = x > 0.f ? x : expm1f(x);
  }
  *(f32x4*)(out + (size_t)r * FDIM + f4 * 4) = o;
}

extern "C" void kernel_launch(void* const* d_in, const int* in_sizes, int n_in,
                              void* d_out, int out_size, void* d_ws, size_t ws_size,
                              hipStream_t stream) {
  const float* h = (const float*)d_in[0];
  const int* adj = (const int*)d_in[1];
  const float* W = (const float*)d_in[2];
  const float* a = (const float*)d_in[3];
  float* out = (float*)d_out;
  char* ws = (char*)d_ws;
  f16* WhT = (f16*)(ws + WS_WHT);
  f16* Bp = (f16*)(ws + WS_BP);
  float2* s12 = (float2*)(ws + WS_S12);
  float2* K12 = (float2*)(ws + WS_K12);
  f16* Eh = (f16*)(ws + WS_EF);
  f16* Fh = (f16*)(ws + WS_EF + 16u * 1024u);
  unsigned* M2 = (unsigned*)(ws + WS_M2);

  const size_t partial_bytes = (size_t)NROW * FDIM * 4;  // 4 MiB per chunk
  int S = (ws_size >= WS_PWS + 8 * partial_bytes + 8 * NROW * 4) ? 8 : 2;
  float* Pws = (float*)(ws + WS_PWS);
  float* Dws = (float*)(ws + WS_PWS + (size_t)S * partial_bytes);
  int jspan = NROW / S;

  k1_wh<<<dim3(256), dim3(256), 0, stream>>>(h, W, WhT, Bp, M2);
  k1b_s<<<dim3(128), dim3(256), 0, stream>>>(WhT, a, s12, M2);
  k1c_prep<<<dim3(32), dim3(256), 0, stream>>>(s12, M2, K12, Eh, Fh);
  k2_main<<<dim3(128 * S), dim3(256), 0, stream>>>(adj, Bp, K12, Eh, Fh, Pws, Dws, jspan);
  k3_comb<<<dim3(1024), dim3(256), 0, stream>>>(Pws, Dws, out, S);
}

// Round 7
// 466.145 us; speedup vs baseline: 1.0237x; 1.0090x over previous
//
#include <hip/hip_runtime.h>
#include <cstdint>
#include <cstddef>

// GAT layer, N=8192, F=128.  Round 7: fix R6 staging-address bug (packed-byte offset
// was qq*1024 [source-int offset], must be qq*256 [packed-byte offset] -> LDS row
// overflow corrupted 3/4 of each row). Structure otherwise identical to R6:
// Phase 1 reads adj in whole-row 1KB-contiguous bursts (memcpy-shaped), packs to
// bytes in LDS; phase 2 feeds MFMAs from LDS. 1 wave/block, no barriers.

#define NROW 8192
#define FDIM 128

typedef _Float16 f16;
typedef f16 f16x8 __attribute__((ext_vector_type(8)));
typedef float f32x4 __attribute__((ext_vector_type(4)));

// workspace byte offsets
#define WS_WHT 0u                            // f16 WhT[128][8192]        : 2 MiB
#define WS_BP  (2u*1024u*1024u)              // f16 Bp[256][8][64][8]     : 2 MiB
#define WS_S12 (4u*1024u*1024u)              // float2 s12[8192]          : 64 KiB
#define WS_K12 (WS_S12 + 64u*1024u)          // float2 K12[8192]          : 64 KiB
#define WS_EF  (WS_K12 + 64u*1024u)          // f16 Eh[8192]; f16 Fh[8192]: 32 KiB
#define WS_M2  (WS_EF + 64u*1024u)           // unsigned M2 key (pad 4K)
#define WS_PWS (WS_M2 + 4u*1024u)            // float Pws[S][8192][128]   : S*4 MiB

// ---------------- k1: Wh = h @ W; write WhT fp16 and Bp ----------------
__global__ __launch_bounds__(256) void k1_wh(const float* __restrict__ h,
                                             const float* __restrict__ W,
                                             f16* __restrict__ WhT,
                                             f16* __restrict__ Bp,
                                             unsigned* __restrict__ M2key) {
  __shared__ float hT[128 * 36];  // hT[k][r], stride 36
  const int t = (int)threadIdx.x;
  const int rb = (int)blockIdx.x * 32;
  if (blockIdx.x == 0 && t == 0) *M2key = 0u;
  const f32x4* hv = (const f32x4*)(h + (size_t)rb * FDIM);
#pragma unroll
  for (int i = 0; i < 4; ++i) {
    int fidx = t + i * 256;
    f32x4 v = hv[fidx];
    int e0 = fidx * 4;
    int r = e0 >> 7, k = e0 & 127;
    hT[(k + 0) * 36 + r] = v[0];
    hT[(k + 1) * 36 + r] = v[1];
    hT[(k + 2) * 36 + r] = v[2];
    hT[(k + 3) * 36 + r] = v[3];
  }
  __syncthreads();
  const int f = t & 127, rh = t >> 7;
  f32x4 z = {0.f, 0.f, 0.f, 0.f};
  f32x4 acc0 = z, acc1 = z, acc2 = z, acc3 = z;
  for (int k = 0; k < 128; ++k) {
    float w = W[k * FDIM + f];
    const f32x4* hp = (const f32x4*)(hT + k * 36 + rh * 16);
    acc0 += hp[0] * w;
    acc1 += hp[1] * w;
    acc2 += hp[2] * w;
    acc3 += hp[3] * w;
  }
  union { f16 hx[16]; uint4 u[2]; } pk;
#pragma unroll
  for (int q = 0; q < 4; ++q) {
    pk.hx[0 + q]  = (f16)acc0[q];   // hx[i] = Wh[rb + rh*16 + i][f]
    pk.hx[4 + q]  = (f16)acc1[q];
    pk.hx[8 + q]  = (f16)acc2[q];
    pk.hx[12 + q] = (f16)acc3[q];
  }
  // WhT [f][row]
  uint4* dst = (uint4*)(WhT + (size_t)f * NROW + rb + rh * 16);
  dst[0] = pk.u[0];
  dst[1] = pk.u[1];
  // Bp[jt=row/32][nt=f/16][lane=q*16+(f&15)][e] = Wh[jt*32 + q*8 + e][f]
  f16* bdst = Bp + (size_t)blockIdx.x * 4096 + (size_t)(f >> 4) * 512
                 + (size_t)(2 * rh) * 128 + (size_t)(f & 15) * 8;
  *(uint4*)bdst = pk.u[0];          // q = 2*rh
  *(uint4*)(bdst + 128) = pk.u[1];  // q = 2*rh + 1
}

// ---------------- k1b: s1,s2 per row (f-split x4); encoded atomicMax M2 ----------------
__global__ __launch_bounds__(256) void k1b_s(const f16* __restrict__ WhT,
                                             const float* __restrict__ a,
                                             float2* __restrict__ s12,
                                             unsigned* __restrict__ M2key) {
  __shared__ float part[2][4][64];
  const int l = (int)threadIdx.x & 63;
  const int fc = (int)threadIdx.x >> 6;
  const int r = (int)blockIdx.x * 64 + l;
  float s1 = 0.f, s2 = 0.f;
  for (int f = fc * 32; f < fc * 32 + 32; ++f) {
    float w = (float)WhT[(size_t)f * NROW + r];
    s1 = fmaf(w, a[f], s1);
    s2 = fmaf(w, a[128 + f], s2);
  }
  part[0][fc][l] = s1;
  part[1][fc][l] = s2;
  __syncthreads();
  if (fc == 0) {
    s1 = part[0][0][l] + part[0][1][l] + part[0][2][l] + part[0][3][l];
    s2 = part[1][0][l] + part[1][1][l] + part[1][2][l] + part[1][3][l];
    s12[r] = make_float2(s1, s2);
    float mx = s2;
#pragma unroll
    for (int off = 32; off; off >>= 1) mx = fmaxf(mx, __shfl_xor(mx, off, 64));
    if (l == 0) {
      unsigned key = __float_as_uint(mx);
      key = (key & 0x80000000u) ? ~key : (key | 0x80000000u);
      atomicMax(M2key, key);
    }
  }
}

// ---------------- k1c: rescaled per-index exp factors (all in (0,1], f16-safe) ----------
__global__ __launch_bounds__(256) void k1c_prep(const float2* __restrict__ s12,
                                                const unsigned* __restrict__ M2key,
                                                float2* __restrict__ K12,
                                                f16* __restrict__ Eh,
                                                f16* __restrict__ Fh) {
  int j = (int)blockIdx.x * 256 + (int)threadIdx.x;
  unsigned key = *M2key;
  float M2 = (key & 0x80000000u) ? __uint_as_float(key ^ 0x80000000u)
                                 : __uint_as_float(~key);
  float2 s = s12[j];
  float u = s.x + M2;
  K12[j] = make_float2(__expf(fminf(0.f, 0.8f * u)), __expf(-0.8f * fmaxf(u, 0.f)));
  Eh[j] = (f16)__expf(s.y - M2);
  Fh[j] = (f16)__expf(0.2f * (s.y - M2));
}

// ---------------- k2: staged-burst fused masked-softmax @ Wh ----------------
// 1 wave/block. block b: rg = b&511 (rows rb..rb+15), c = b>>9 (j chunk).
// Window = 1024 j. Phase 1: adj rows in 1KB-contiguous bursts -> byte-pack -> LDS.
// Phase 2: 32 iters x 32 j: masks from LDS, E/F+B 1-ahead reg prefetch, 9 MFMA.
__global__ __launch_bounds__(64) void k2_main(const int* __restrict__ adj,
                                              const f16* __restrict__ Bp,
                                              const float2* __restrict__ K12,
                                              const f16* __restrict__ Eh,
                                              const f16* __restrict__ Fh,
                                              float* __restrict__ Pws,
                                              float* __restrict__ Dws,
                                              int jspan) {
  __shared__ char mbuf[16 * 1040];  // [row][1024 packed j bytes + 16 pad]
  const int L = (int)threadIdx.x;
  const int b = (int)blockIdx.x;
  const int rg = b & 511;
  const int c = b >> 9;
  const int rb = rg * 16;
  const int m = L & 15, kq = L >> 4;
  const int row = rb + m;
  const int j0 = c * jspan;

  const float2 kk = K12[row];
  f16x8 kap1v, kap2v, bones;
#pragma unroll
  for (int i = 0; i < 8; ++i) {
    kap1v[i] = (f16)kk.x;
    kap2v[i] = (f16)kk.y;
    bones[i] = (f16)1.0f;
  }

  f32x4 z = {0.f, 0.f, 0.f, 0.f};
  f32x4 acc[8] = {z, z, z, z, z, z, z, z};
  f32x4 accd = z;

  for (int wb = 0; wb < jspan; wb += 1024) {
    const int jw = j0 + wb;

    // ---- phase 1: stage 16 rows x 1024 j, whole-row contiguous bursts ----
    // round r covers rows 2r,2r+1: 8 int4 loads, each = 64 lanes x 16B = 1KB of ONE row.
    const int* abase = adj + (size_t)rb * NROW + jw;
    int4 Ra[8], Rb8[8];
    auto issue = [&](int r, int4* dst) {
#pragma unroll
      for (int q = 0; q < 8; ++q) {
        int rr = 2 * r + (q >> 2), qq = q & 3;
        dst[q] = *(const int4*)(abase + (size_t)rr * NROW + qq * 256 + L * 4);
      }
    };
    auto packwrite = [&](int r, const int4* src) {
#pragma unroll
      for (int q = 0; q < 8; ++q) {
        int rr = 2 * r + (q >> 2), qq = q & 3;
        int4 v = src[q];  // adj values are 0/1 -> bytes directly
        unsigned pb = (unsigned)v.x | ((unsigned)v.y << 8) |
                      ((unsigned)v.z << 16) | ((unsigned)v.w << 24);
        // R7 fix: packed-byte offset is qq*256 (quarter of 1024 bytes), was qq*1024
        *(unsigned*)(mbuf + rr * 1040 + qq * 256 + L * 4) = pb;
      }
    };
    issue(0, Ra);
    issue(1, Rb8);
    packwrite(0, Ra); issue(2, Ra);
    packwrite(1, Rb8); issue(3, Rb8);
    packwrite(2, Ra); issue(4, Ra);
    packwrite(3, Rb8); issue(5, Rb8);
    packwrite(4, Ra); issue(6, Ra);
    packwrite(5, Rb8); issue(7, Rb8);
    packwrite(6, Ra);
    packwrite(7, Rb8);
    // single wave: ds_write -> ds_read ordering handled by lgkmcnt (no barrier)

    // ---- phase 2: 32 iters of 32 j ----
    const f16* bt0 = Bp + (size_t)(jw >> 5) * 4096 + (size_t)L * 8;
    const f16* ehp = Eh + jw + kq * 8;
    const f16* fhp = Fh + jw + kq * 8;
    const char* mrow = mbuf + m * 1040 + kq * 8;

    f16x8 Ecur = *(const f16x8*)(ehp);
    f16x8 Fcur = *(const f16x8*)(fhp);
    uint2 mkc = *(const uint2*)(mrow);

    for (int it = 0; it < 32; ++it) {
      // B loads first (L2) — MFMAs below wait only on these
      const f16* bt = bt0 + (size_t)it * 4096;
      f16x8 B0 = *(const f16x8*)(bt);
      f16x8 B1 = *(const f16x8*)(bt + 512);
      f16x8 B2 = *(const f16x8*)(bt + 1024);
      f16x8 B3 = *(const f16x8*)(bt + 1536);
      f16x8 B4 = *(const f16x8*)(bt + 2048);
      f16x8 B5 = *(const f16x8*)(bt + 2560);
      f16x8 B6 = *(const f16x8*)(bt + 3072);
      f16x8 B7 = *(const f16x8*)(bt + 3584);

      // score from regs prefetched last iter
      f16x8 t = __builtin_elementwise_max(Ecur * kap1v, Fcur * kap2v);
      f16x8 af;
      af[0] = (mkc.x & 0x000000FFu) ? t[0] : (f16)0.f;
      af[1] = (mkc.x & 0x0000FF00u) ? t[1] : (f16)0.f;
      af[2] = (mkc.x & 0x00FF0000u) ? t[2] : (f16)0.f;
      af[3] = (mkc.x & 0xFF000000u) ? t[3] : (f16)0.f;
      af[4] = (mkc.y & 0x000000FFu) ? t[4] : (f16)0.f;
      af[5] = (mkc.y & 0x0000FF00u) ? t[5] : (f16)0.f;
      af[6] = (mkc.y & 0x00FF0000u) ? t[6] : (f16)0.f;
      af[7] = (mkc.y & 0xFF000000u) ? t[7] : (f16)0.f;

      // prefetch next iter's mask (LDS) and E/F (L2)
      const int itn = (it + 1 < 32) ? it + 1 : it;
      mkc = *(const uint2*)(mrow + itn * 32);
      Ecur = *(const f16x8*)(ehp + itn * 32);
      Fcur = *(const f16x8*)(fhp + itn * 32);

      acc[0] = __builtin_amdgcn_mfma_f32_16x16x32_f16(af, B0, acc[0], 0, 0, 0);
      acc[1] = __builtin_amdgcn_mfma_f32_16x16x32_f16(af, B1, acc[1], 0, 0, 0);
      acc[2] = __builtin_amdgcn_mfma_f32_16x16x32_f16(af, B2, acc[2], 0, 0, 0);
      acc[3] = __builtin_amdgcn_mfma_f32_16x16x32_f16(af, B3, acc[3], 0, 0, 0);
      acc[4] = __builtin_amdgcn_mfma_f32_16x16x32_f16(af, B4, acc[4], 0, 0, 0);
      acc[5] = __builtin_amdgcn_mfma_f32_16x16x32_f16(af, B5, acc[5], 0, 0, 0);
      acc[6] = __builtin_amdgcn_mfma_f32_16x16x32_f16(af, B6, acc[6], 0, 0, 0);
      acc[7] = __builtin_amdgcn_mfma_f32_16x16x32_f16(af, B7, acc[7], 0, 0, 0);
      accd   = __builtin_amdgcn_mfma_f32_16x16x32_f16(af, bones, accd, 0, 0, 0);
    }
  }

  // denominator: accd[reg] = D[row kq*4+reg][col m]; all cols equal, take m==0
  if (m == 0) {
#pragma unroll
    for (int reg = 0; reg < 4; ++reg)
      Dws[(size_t)c * NROW + rb + kq * 4 + reg] = accd[reg];
  }

  // numerator partials: C/D layout col=m, row=kq*4+reg
  float* P = Pws + ((size_t)c * NROW + rb) * FDIM + m;
#pragma unroll
  for (int nt = 0; nt < 8; ++nt) {
#pragma unroll
    for (int reg = 0; reg < 4; ++reg) {
      int rr = kq * 4 + reg;
      P[(size_t)rr * FDIM + nt * 16] = acc[nt][reg];
    }
  }
}

// ---------------- k3: combine S partials, ELU ----------------
__global__ __launch_bounds__(256) void k3_comb(const float* __restrict__ Pws,
                                               const float* __restrict__ Dws,
                                               float* __restrict__ out, int S) {
  int g = (int)blockIdx.x * 256 + (int)threadIdx.x;  // 0..262143
  int r = g >> 5, f4 = g & 31;
  f32x4 s = {0.f, 0.f, 0.f, 0.f};
  float den = 0.f;
  for (int c2 = 0; c2 < S; ++c2) {
    s += *(const f32x4*)(Pws + ((size_t)c2 * NROW + r) * FDIM + f4 * 4);
    den += Dws[(size_t)c2 * NROW + r];
  }
  float inv = 1.0f / den;
  f32x4 o;
#pragma unroll
  for (int e = 0; e < 4; ++e) {
    float x = s[e] * inv;
    o[e] = x > 0.f ? x : expm1f(x);
  }
  *(f32x4*)(out + (size_t)r * FDIM + f4 * 4) = o;
}

extern "C" void kernel_launch(void* const* d_in, const int* in_sizes, int n_in,
                              void* d_out, int out_size, void* d_ws, size_t ws_size,
                              hipStream_t stream) {
  const float* h = (const float*)d_in[0];
  const int* adj = (const int*)d_in[1];
  const float* W = (const float*)d_in[2];
  const float* a = (const float*)d_in[3];
  float* out = (float*)d_out;
  char* ws = (char*)d_ws;
  f16* WhT = (f16*)(ws + WS_WHT);
  f16* Bp = (f16*)(ws + WS_BP);
  float2* s12 = (float2*)(ws + WS_S12);
  float2* K12 = (float2*)(ws + WS_K12);
  f16* Eh = (f16*)(ws + WS_EF);
  f16* Fh = (f16*)(ws + WS_EF + 16u * 1024u);
  unsigned* M2 = (unsigned*)(ws + WS_M2);

  const size_t partial_bytes = (size_t)NROW * FDIM * 4;  // 4 MiB per chunk
  int S = (ws_size >= WS_PWS + 8 * partial_bytes + 8 * NROW * 4) ? 8 : 2;
  float* Pws = (float*)(ws + WS_PWS);
  float* Dws = (float*)(ws + WS_PWS + (size_t)S * partial_bytes);
  int jspan = NROW / S;

  k1_wh<<<dim3(256), dim3(256), 0, stream>>>(h, W, WhT, Bp, M2);
  k1b_s<<<dim3(128), dim3(256), 0, stream>>>(WhT, a, s12, M2);
  k1c_prep<<<dim3(32), dim3(256), 0, stream>>>(s12, M2, K12, Eh, Fh);
  k2_main<<<dim3(512 * S), dim3(64), 0, stream>>>(adj, Bp, K12, Eh, Fh, Pws, Dws, jspan);
  k3_comb<<<dim3(1024), dim3(256), 0, stream>>>(Pws, Dws, out, S);
}

// Round 8
// 457.808 us; speedup vs baseline: 1.0423x; 1.0182x over previous
//
#include <hip/hip_runtime.h>
#include <cstdint>
#include <cstddef>

// GAT layer, N=8192, F=128.  Round 8: adj -> 8MB bitmask via memcpy-shaped k0.
// R3-R7 invariant: four different k2 structures all deliver ~1.6 TB/s on the 268 MB
// adj read with every pipe idle. Fix + decisive probe: compress adj 32:1 in k0
// (ballot-pack, pure sequential reads = the proven 6.3 TB/s regime), then k2 reads
// only cache-resident data (Bp 2MiB, EF 32KB, pmask 8MB). k2: no LDS, no barriers.

#define NROW 8192
#define FDIM 128

typedef _Float16 f16;
typedef f16 f16x8 __attribute__((ext_vector_type(8)));
typedef float f32x4 __attribute__((ext_vector_type(4)));
typedef unsigned long long u64;

// workspace byte offsets
#define WS_WHT 0u                            // f16 WhT[128][8192]        : 2 MiB
#define WS_BP  (2u*1024u*1024u)              // f16 Bp[256][8][64][8]     : 2 MiB
#define WS_S12 (4u*1024u*1024u)              // float2 s12[8192]          : 64 KiB
#define WS_K12 (WS_S12 + 64u*1024u)          // float2 K12[8192]          : 64 KiB
#define WS_EF  (WS_K12 + 64u*1024u)          // f16 Eh[8192]; f16 Fh[8192]: 32 KiB
#define WS_M2  (WS_EF + 64u*1024u)           // unsigned M2 key (pad 4K)
#define WS_PM  (WS_M2 + 4u*1024u)            // u64 pmask[8192][128]      : 8 MiB
#define WS_PWS (WS_PM + 8u*1024u*1024u)      // float Pws[S][8192][128]   : S*4 MiB

// ---------------- k0: ballot-pack adj (268MB, sequential) -> bitmask (8MB) ----------
// 1 wave = 1 row. Round r: lane L reads adj[row][r*64+L] (256B/instr contiguous),
// ballot -> u64 (bit L = j=r*64+L). 8 rounds batched; lanes 0..7 store 64B together.
__global__ __launch_bounds__(256) void k0_pack(const int* __restrict__ adj,
                                               u64* __restrict__ pm64) {
  const int L = (int)threadIdx.x & 63;
  const int w = (int)threadIdx.x >> 6;
  const int row = (int)blockIdx.x * 4 + w;
  const int* ap = adj + (size_t)row * NROW + L;
  u64* dp = pm64 + (size_t)row * 128;
  for (int r8 = 0; r8 < 128; r8 += 8) {
    int v0 = ap[(r8 + 0) * 64];
    int v1 = ap[(r8 + 1) * 64];
    int v2 = ap[(r8 + 2) * 64];
    int v3 = ap[(r8 + 3) * 64];
    int v4 = ap[(r8 + 4) * 64];
    int v5 = ap[(r8 + 5) * 64];
    int v6 = ap[(r8 + 6) * 64];
    int v7 = ap[(r8 + 7) * 64];
    u64 b0 = __ballot(v0 > 0);
    u64 b1 = __ballot(v1 > 0);
    u64 b2 = __ballot(v2 > 0);
    u64 b3 = __ballot(v3 > 0);
    u64 b4 = __ballot(v4 > 0);
    u64 b5 = __ballot(v5 > 0);
    u64 b6 = __ballot(v6 > 0);
    u64 b7 = __ballot(v7 > 0);
    // lane i<8 stores b[i] -> 64B contiguous store
    u64 s01 = (L & 1) ? b1 : b0;
    u64 s23 = (L & 1) ? b3 : b2;
    u64 s45 = (L & 1) ? b5 : b4;
    u64 s67 = (L & 1) ? b7 : b6;
    u64 s03 = (L & 2) ? s23 : s01;
    u64 s47 = (L & 2) ? s67 : s45;
    u64 mv = (L & 4) ? s47 : s03;
    if (L < 8) dp[r8 + L] = mv;
  }
}

// ---------------- k1: Wh = h @ W; write WhT fp16 and Bp ----------------
__global__ __launch_bounds__(256) void k1_wh(const float* __restrict__ h,
                                             const float* __restrict__ W,
                                             f16* __restrict__ WhT,
                                             f16* __restrict__ Bp,
                                             unsigned* __restrict__ M2key) {
  __shared__ float hT[128 * 36];  // hT[k][r], stride 36
  const int t = (int)threadIdx.x;
  const int rb = (int)blockIdx.x * 32;
  if (blockIdx.x == 0 && t == 0) *M2key = 0u;
  const f32x4* hv = (const f32x4*)(h + (size_t)rb * FDIM);
#pragma unroll
  for (int i = 0; i < 4; ++i) {
    int fidx = t + i * 256;
    f32x4 v = hv[fidx];
    int e0 = fidx * 4;
    int r = e0 >> 7, k = e0 & 127;
    hT[(k + 0) * 36 + r] = v[0];
    hT[(k + 1) * 36 + r] = v[1];
    hT[(k + 2) * 36 + r] = v[2];
    hT[(k + 3) * 36 + r] = v[3];
  }
  __syncthreads();
  const int f = t & 127, rh = t >> 7;
  f32x4 z = {0.f, 0.f, 0.f, 0.f};
  f32x4 acc0 = z, acc1 = z, acc2 = z, acc3 = z;
  for (int k = 0; k < 128; ++k) {
    float w = W[k * FDIM + f];
    const f32x4* hp = (const f32x4*)(hT + k * 36 + rh * 16);
    acc0 += hp[0] * w;
    acc1 += hp[1] * w;
    acc2 += hp[2] * w;
    acc3 += hp[3] * w;
  }
  union { f16 hx[16]; uint4 u[2]; } pk;
#pragma unroll
  for (int q = 0; q < 4; ++q) {
    pk.hx[0 + q]  = (f16)acc0[q];   // hx[i] = Wh[rb + rh*16 + i][f]
    pk.hx[4 + q]  = (f16)acc1[q];
    pk.hx[8 + q]  = (f16)acc2[q];
    pk.hx[12 + q] = (f16)acc3[q];
  }
  // WhT [f][row]
  uint4* dst = (uint4*)(WhT + (size_t)f * NROW + rb + rh * 16);
  dst[0] = pk.u[0];
  dst[1] = pk.u[1];
  // Bp[jt=row/32][nt=f/16][lane=q*16+(f&15)][e] = Wh[jt*32 + q*8 + e][f]
  f16* bdst = Bp + (size_t)blockIdx.x * 4096 + (size_t)(f >> 4) * 512
                 + (size_t)(2 * rh) * 128 + (size_t)(f & 15) * 8;
  *(uint4*)bdst = pk.u[0];          // q = 2*rh
  *(uint4*)(bdst + 128) = pk.u[1];  // q = 2*rh + 1
}

// ---------------- k1b: s1,s2 per row (f-split x4); encoded atomicMax M2 ----------------
__global__ __launch_bounds__(256) void k1b_s(const f16* __restrict__ WhT,
                                             const float* __restrict__ a,
                                             float2* __restrict__ s12,
                                             unsigned* __restrict__ M2key) {
  __shared__ float part[2][4][64];
  const int l = (int)threadIdx.x & 63;
  const int fc = (int)threadIdx.x >> 6;
  const int r = (int)blockIdx.x * 64 + l;
  float s1 = 0.f, s2 = 0.f;
  for (int f = fc * 32; f < fc * 32 + 32; ++f) {
    float w = (float)WhT[(size_t)f * NROW + r];
    s1 = fmaf(w, a[f], s1);
    s2 = fmaf(w, a[128 + f], s2);
  }
  part[0][fc][l] = s1;
  part[1][fc][l] = s2;
  __syncthreads();
  if (fc == 0) {
    s1 = part[0][0][l] + part[0][1][l] + part[0][2][l] + part[0][3][l];
    s2 = part[1][0][l] + part[1][1][l] + part[1][2][l] + part[1][3][l];
    s12[r] = make_float2(s1, s2);
    float mx = s2;
#pragma unroll
    for (int off = 32; off; off >>= 1) mx = fmaxf(mx, __shfl_xor(mx, off, 64));
    if (l == 0) {
      unsigned key = __float_as_uint(mx);
      key = (key & 0x80000000u) ? ~key : (key | 0x80000000u);
      atomicMax(M2key, key);
    }
  }
}

// ---------------- k1c: rescaled per-index exp factors (all in (0,1], f16-safe) ----------
__global__ __launch_bounds__(256) void k1c_prep(const float2* __restrict__ s12,
                                                const unsigned* __restrict__ M2key,
                                                float2* __restrict__ K12,
                                                f16* __restrict__ Eh,
                                                f16* __restrict__ Fh) {
  int j = (int)blockIdx.x * 256 + (int)threadIdx.x;
  unsigned key = *M2key;
  float M2 = (key & 0x80000000u) ? __uint_as_float(key ^ 0x80000000u)
                                 : __uint_as_float(~key);
  float2 s = s12[j];
  float u = s.x + M2;
  K12[j] = make_float2(__expf(fminf(0.f, 0.8f * u)), __expf(-0.8f * fmaxf(u, 0.f)));
  Eh[j] = (f16)__expf(s.y - M2);
  Fh[j] = (f16)__expf(0.2f * (s.y - M2));
}

// ---------------- k2: fused masked-softmax @ Wh, all traffic cache-resident ----------
// 1 wave/block, no LDS. block b: rg=b&511 (16 rows), c=b>>9 (j chunk).
// lane: m=L&15 (row), kq=L>>4. iter it: 32 j. mask = one broadcast dword
// pm32[row][j/32] (byte kq = lane's 8 bits). E/F+mask prefetched 1 iter ahead.
__global__ __launch_bounds__(64) void k2_main(const unsigned* __restrict__ pm32,
                                              const f16* __restrict__ Bp,
                                              const float2* __restrict__ K12,
                                              const f16* __restrict__ Eh,
                                              const f16* __restrict__ Fh,
                                              float* __restrict__ Pws,
                                              float* __restrict__ Dws,
                                              int jspan) {
  const int L = (int)threadIdx.x;
  const int b = (int)blockIdx.x;
  const int rg = b & 511;
  const int c = b >> 9;
  const int rb = rg * 16;
  const int m = L & 15, kq = L >> 4;
  const int row = rb + m;
  const int j0 = c * jspan;
  const int niter = jspan >> 5;

  const float2 kk = K12[row];
  f16x8 kap1v, kap2v, bones;
#pragma unroll
  for (int i = 0; i < 8; ++i) {
    kap1v[i] = (f16)kk.x;
    kap2v[i] = (f16)kk.y;
    bones[i] = (f16)1.0f;
  }

  const unsigned* pmrow = pm32 + (size_t)row * 256 + (j0 >> 5);
  const f16* ehp = Eh + j0 + kq * 8;
  const f16* fhp = Fh + j0 + kq * 8;
  const f16* bt0 = Bp + (size_t)(j0 >> 5) * 4096 + (size_t)L * 8;

  unsigned mkc = pmrow[0];
  f16x8 Ecur = *(const f16x8*)(ehp);
  f16x8 Fcur = *(const f16x8*)(fhp);

  f32x4 z = {0.f, 0.f, 0.f, 0.f};
  f32x4 acc[8] = {z, z, z, z, z, z, z, z};
  f32x4 accd = z;

  for (int it = 0; it < niter; ++it) {
    // B loads first (L2) — MFMAs below wait only on these
    const f16* bt = bt0 + (size_t)it * 4096;
    f16x8 B0 = *(const f16x8*)(bt);
    f16x8 B1 = *(const f16x8*)(bt + 512);
    f16x8 B2 = *(const f16x8*)(bt + 1024);
    f16x8 B3 = *(const f16x8*)(bt + 1536);
    f16x8 B4 = *(const f16x8*)(bt + 2048);
    f16x8 B5 = *(const f16x8*)(bt + 2560);
    f16x8 B6 = *(const f16x8*)(bt + 3072);
    f16x8 B7 = *(const f16x8*)(bt + 3584);

    // score from regs prefetched last iter; lane's 8 mask bits = byte kq of mkc
    f16x8 t = __builtin_elementwise_max(Ecur * kap1v, Fcur * kap2v);
    const unsigned msh = mkc >> (kq * 8);
    f16x8 af;
    af[0] = (msh & 1u)   ? t[0] : (f16)0.f;
    af[1] = (msh & 2u)   ? t[1] : (f16)0.f;
    af[2] = (msh & 4u)   ? t[2] : (f16)0.f;
    af[3] = (msh & 8u)   ? t[3] : (f16)0.f;
    af[4] = (msh & 16u)  ? t[4] : (f16)0.f;
    af[5] = (msh & 32u)  ? t[5] : (f16)0.f;
    af[6] = (msh & 64u)  ? t[6] : (f16)0.f;
    af[7] = (msh & 128u) ? t[7] : (f16)0.f;

    // prefetch next iter's mask + E/F (all L2/L3-resident)
    const int itn = (it + 1 < niter) ? it + 1 : it;
    mkc = pmrow[itn];
    Ecur = *(const f16x8*)(ehp + itn * 32);
    Fcur = *(const f16x8*)(fhp + itn * 32);

    acc[0] = __builtin_amdgcn_mfma_f32_16x16x32_f16(af, B0, acc[0], 0, 0, 0);
    acc[1] = __builtin_amdgcn_mfma_f32_16x16x32_f16(af, B1, acc[1], 0, 0, 0);
    acc[2] = __builtin_amdgcn_mfma_f32_16x16x32_f16(af, B2, acc[2], 0, 0, 0);
    acc[3] = __builtin_amdgcn_mfma_f32_16x16x32_f16(af, B3, acc[3], 0, 0, 0);
    acc[4] = __builtin_amdgcn_mfma_f32_16x16x32_f16(af, B4, acc[4], 0, 0, 0);
    acc[5] = __builtin_amdgcn_mfma_f32_16x16x32_f16(af, B5, acc[5], 0, 0, 0);
    acc[6] = __builtin_amdgcn_mfma_f32_16x16x32_f16(af, B6, acc[6], 0, 0, 0);
    acc[7] = __builtin_amdgcn_mfma_f32_16x16x32_f16(af, B7, acc[7], 0, 0, 0);
    accd   = __builtin_amdgcn_mfma_f32_16x16x32_f16(af, bones, accd, 0, 0, 0);
  }

  // denominator: accd[reg] = D[row kq*4+reg][col m]; all cols equal, take m==0
  if (m == 0) {
#pragma unroll
    for (int reg = 0; reg < 4; ++reg)
      Dws[(size_t)c * NROW + rb + kq * 4 + reg] = accd[reg];
  }

  // numerator partials: C/D layout col=m, row=kq*4+reg
  float* P = Pws + ((size_t)c * NROW + rb) * FDIM + m;
#pragma unroll
  for (int nt = 0; nt < 8; ++nt) {
#pragma unroll
    for (int reg = 0; reg < 4; ++reg) {
      int rr = kq * 4 + reg;
      P[(size_t)rr * FDIM + nt * 16] = acc[nt][reg];
    }
  }
}

// ---------------- k3: combine S partials, ELU ----------------
__global__ __launch_bounds__(256) void k3_comb(const float* __restrict__ Pws,
                                               const float* __restrict__ Dws,
                                               float* __restrict__ out, int S) {
  int g = (int)blockIdx.x * 256 + (int)threadIdx.x;  // 0..262143
  int r = g >> 5, f4 = g & 31;
  f32x4 s = {0.f, 0.f, 0.f, 0.f};
  float den = 0.f;
  for (int c2 = 0; c2 < S; ++c2) {
    s += *(const f32x4*)(Pws + ((size_t)c2 * NROW + r) * FDIM + f4 * 4);
    den += Dws[(size_t)c2 * NROW + r];
  }
  float inv = 1.0f / den;
  f32x4 o;
#pragma unroll
  for (int e = 0; e < 4; ++e) {
    float x = s[e] * inv;
    o[e] = x > 0.f ? x : expm1f(x);
  }
  *(f32x4*)(out + (size_t)r * FDIM + f4 * 4) = o;
}

extern "C" void kernel_launch(void* const* d_in, const int* in_sizes, int n_in,
                              void* d_out, int out_size, void* d_ws, size_t ws_size,
                              hipStream_t stream) {
  const float* h = (const float*)d_in[0];
  const int* adj = (const int*)d_in[1];
  const float* W = (const float*)d_in[2];
  const float* a = (const float*)d_in[3];
  float* out = (float*)d_out;
  char* ws = (char*)d_ws;
  f16* WhT = (f16*)(ws + WS_WHT);
  f16* Bp = (f16*)(ws + WS_BP);
  float2* s12 = (float2*)(ws + WS_S12);
  float2* K12 = (float2*)(ws + WS_K12);
  f16* Eh = (f16*)(ws + WS_EF);
  f16* Fh = (f16*)(ws + WS_EF + 16u * 1024u);
  unsigned* M2 = (unsigned*)(ws + WS_M2);
  u64* pm64 = (u64*)(ws + WS_PM);

  const size_t partial_bytes = (size_t)NROW * FDIM * 4;  // 4 MiB per chunk
  int S = (ws_size >= WS_PWS + 8 * partial_bytes + 8 * NROW * 4) ? 8 : 2;
  float* Pws = (float*)(ws + WS_PWS);
  float* Dws = (float*)(ws + WS_PWS + (size_t)S * partial_bytes);
  int jspan = NROW / S;

  k0_pack<<<dim3(2048), dim3(256), 0, stream>>>(adj, pm64);
  k1_wh<<<dim3(256), dim3(256), 0, stream>>>(h, W, WhT, Bp, M2);
  k1b_s<<<dim3(128), dim3(256), 0, stream>>>(WhT, a, s12, M2);
  k1c_prep<<<dim3(32), dim3(256), 0, stream>>>(s12, M2, K12, Eh, Fh);
  k2_main<<<dim3(512 * S), dim3(64), 0, stream>>>((const unsigned*)pm64, Bp, K12, Eh, Fh,
                                                  Pws, Dws, jspan);
  k3_comb<<<dim3(1024), dim3(256), 0, stream>>>(Pws, Dws, out, S);
}